// Round 1
// baseline (841.386 us; speedup 1.0000x reference)
//
#include <hip/hip_runtime.h>
#include <math.h>

#define B_DIM 128
#define T_DIM 50
#define LEAF  4880
#define A_DIM 64
#define ATTN  128
#define RNN   128
#define NC    283
#define M_TOT (B_DIM*T_DIM)   // 6400

__device__ __forceinline__ float sigmoidf_(float x) {
  return 1.0f / (1.0f + __expf(-x));
}

// ---------------------------------------------------------------------------
// K1: X[6400,128] = tanh(Ax[6400,4880] @ Wd[4880,128])
// BM=32, BN=128, BK=40 (4880 = 122*40), 256 threads, grid 200
// ---------------------------------------------------------------------------
__global__ __launch_bounds__(256) void k_tanh_gemm(
    const float* __restrict__ Ax, const float* __restrict__ Wd,
    float* __restrict__ X) {
  __shared__ __align__(16) float As[32][44];   // pad 40 -> 44
  __shared__ __align__(16) float Bs[40][128];
  const int tid = threadIdx.x;
  const int m0  = blockIdx.x * 32;
  const int ng  = tid & 31;   // n = ng*4
  const int mg  = tid >> 5;   // m = mg*4 + r

  // A staging indices (hoisted): 320 float4 per tile, phase0: all 256, phase1: tid<64
  const int rowA0 = tid / 10, k4A0 = tid % 10;
  const int rowA1 = (tid + 256) / 10, k4A1 = (tid + 256) % 10;
  const bool ph1 = (tid + 256) < 320;
  const float* pA0 = Ax + (size_t)(m0 + rowA0) * LEAF + k4A0 * 4;
  const float* pA1 = Ax + (size_t)(m0 + rowA1) * LEAF + k4A1 * 4;
  // B staging indices: 1280 float4 per tile, 5 per thread
  const int brb = tid >> 5, b4 = tid & 31;
  const float* pB = Wd + (size_t)brb * 128 + b4 * 4;

  float4 acc[4];
  #pragma unroll
  for (int r = 0; r < 4; ++r) acc[r] = make_float4(0.f, 0.f, 0.f, 0.f);

  for (int kt = 0; kt < 122; ++kt) {
    // stage A tile
    {
      float4 v = *(const float4*)pA0;
      *(float4*)&As[rowA0][k4A0 * 4] = v;
      if (ph1) {
        float4 w = *(const float4*)pA1;
        *(float4*)&As[rowA1][k4A1 * 4] = w;
      }
    }
    // stage B tile
    #pragma unroll
    for (int i = 0; i < 5; ++i) {
      float4 v = *(const float4*)(pB + (size_t)i * 8 * 128);
      *(float4*)&Bs[brb + i * 8][b4 * 4] = v;
    }
    __syncthreads();

    #pragma unroll
    for (int k = 0; k < 40; k += 4) {
      float4 av[4], bv[4];
      #pragma unroll
      for (int r = 0; r < 4; ++r) av[r] = *(const float4*)&As[mg * 4 + r][k];
      #pragma unroll
      for (int kk = 0; kk < 4; ++kk) bv[kk] = *(const float4*)&Bs[k + kk][ng * 4];
      #pragma unroll
      for (int r = 0; r < 4; ++r) {
        float aa[4] = {av[r].x, av[r].y, av[r].z, av[r].w};
        #pragma unroll
        for (int kk = 0; kk < 4; ++kk) {
          acc[r].x += aa[kk] * bv[kk].x;
          acc[r].y += aa[kk] * bv[kk].y;
          acc[r].z += aa[kk] * bv[kk].z;
          acc[r].w += aa[kk] * bv[kk].w;
        }
      }
    }
    __syncthreads();
    pA0 += 40; pA1 += 40; pB += 40 * 128;
  }

  #pragma unroll
  for (int r = 0; r < 4; ++r) {
    float4 o;
    o.x = tanhf(acc[r].x); o.y = tanhf(acc[r].y);
    o.z = tanhf(acc[r].z); o.w = tanhf(acc[r].w);
    *(float4*)&X[(size_t)(m0 + mg * 4 + r) * 128 + ng * 4] = o;
  }
}

// ---------------------------------------------------------------------------
// Generic small GEMM: C[M,N] = A[M,K] @ Bw[N,K]^T + bias  (opt sigmoid*mask)
// BM=32, BN=64, 256 threads. A staged in LDS; B rows streamed from L2.
// ---------------------------------------------------------------------------
template<int K, int ACT>
__global__ __launch_bounds__(256) void k_gemm_bn(
    const float* __restrict__ A, const float* __restrict__ Bw,
    const float* __restrict__ bias, const float* __restrict__ maskv,
    float* __restrict__ C, int N, int ldc) {
  __shared__ __align__(16) float As[32][K + 4];
  const int tid = threadIdx.x;
  const int m0 = blockIdx.x * 32;
  const int n0 = blockIdx.y * 64;
  constexpr int K4 = K / 4;

  #pragma unroll
  for (int i = 0; i < (32 * K4) / 256; ++i) {
    int idx = tid + i * 256;
    int row = idx / K4, k4 = idx % K4;
    float4 v = *(const float4*)&A[(size_t)(m0 + row) * K + k4 * 4];
    *(float4*)&As[row][k4 * 4] = v;
  }
  __syncthreads();

  const int n2 = tid & 31, mg = tid >> 5;
  const int n = n0 + n2 * 2;
  const int ns0 = min(n, N - 1), ns1 = min(n + 1, N - 1);
  const float* Bp0 = Bw + (size_t)ns0 * K;
  const float* Bp1 = Bw + (size_t)ns1 * K;

  float acc[4][2] = {};
  #pragma unroll 4
  for (int k = 0; k < K; k += 4) {
    float4 b0 = *(const float4*)&Bp0[k];
    float4 b1 = *(const float4*)&Bp1[k];
    #pragma unroll
    for (int r = 0; r < 4; ++r) {
      float4 a = *(const float4*)&As[mg * 4 + r][k];
      acc[r][0] += a.x * b0.x + a.y * b0.y + a.z * b0.z + a.w * b0.w;
      acc[r][1] += a.x * b1.x + a.y * b1.y + a.z * b1.z + a.w * b1.w;
    }
  }

  #pragma unroll
  for (int r = 0; r < 4; ++r) {
    int m = m0 + mg * 4 + r;
    #pragma unroll
    for (int c = 0; c < 2; ++c) {
      int nn = n + c;
      if (nn < N) {
        float v = acc[r][c] + bias[nn];
        if (ACT) v = sigmoidf_(v) * maskv[m];
        C[(size_t)m * ldc + nn] = v;
      }
    }
  }
}

// ---------------------------------------------------------------------------
// GRU scan, one layer. One block per batch row; 768 threads.
// Thread pair (g = tid>>1) owns Whh row g; half hf = tid&1 does 64 of the 128 MACs.
// xW = precomputed x@Wih^T + bih, layout [(b*50+t)*384 + g].
// ---------------------------------------------------------------------------
__global__ __launch_bounds__(768) void k_gru(
    const float* __restrict__ xW, const float* __restrict__ Whh,
    const float* __restrict__ bhh, float* __restrict__ Hout) {
  const int b = blockIdx.x;
  const int tid = threadIdx.x;
  const int g = tid >> 1;
  const int hf = tid & 1;
  __shared__ __align__(16) float hs[128];
  __shared__ float ghs[384];

  float4 w4[16];
  #pragma unroll
  for (int k = 0; k < 16; ++k)
    w4[k] = *(const float4*)&Whh[(size_t)g * 128 + hf * 64 + k * 4];
  const float bh = bhh[g];

  if (tid < 128) hs[tid] = 0.0f;
  __syncthreads();

  for (int t = 0; t < 50; ++t) {
    float acc = 0.f;
    #pragma unroll
    for (int k = 0; k < 16; ++k) {
      float4 hv = *(const float4*)&hs[hf * 64 + k * 4];
      acc += w4[k].x * hv.x + w4[k].y * hv.y + w4[k].z * hv.z + w4[k].w * hv.w;
    }
    float other = __shfl_xor(acc, 1);
    acc += other;
    if (hf == 0) ghs[g] = acc + bh;
    __syncthreads();
    if (tid < 128) {
      const int j = tid;
      const float* xw = &xW[(size_t)(b * 50 + t) * 384];
      float r = sigmoidf_(xw[j] + ghs[j]);
      float z = sigmoidf_(xw[128 + j] + ghs[128 + j]);
      float nn = tanhf(xw[256 + j] + r * ghs[256 + j]);
      float h = (1.f - z) * nn + z * hs[j];
      hs[j] = h;
      Hout[(size_t)(b * 50 + t) * 128 + j] = h;
    }
    __syncthreads();
  }
}

// ---------------------------------------------------------------------------
// Attention: per (b,t) block (6400 blocks, 128 threads).
// gather l=embed_a[f], hl=out.l, masked softmax, k=w.l, S=[out|k]
// ---------------------------------------------------------------------------
__global__ __launch_bounds__(128) void k_attn(
    const float* __restrict__ H2, const int* __restrict__ F,
    const float* __restrict__ emb, float* __restrict__ S) {
  const int m = blockIdx.x;
  const int tid = threadIdx.x;
  __shared__ __align__(16) float outs[128];
  __shared__ __align__(16) float Ls[64][132];
  __shared__ float hls[64];
  __shared__ float wts[64];
  __shared__ int fs[64];

  outs[tid] = H2[(size_t)m * 128 + tid];
  if (tid < 64) fs[tid] = F[(size_t)m * 64 + tid];
  __syncthreads();

  #pragma unroll
  for (int i = 0; i < 16; ++i) {
    int idx = tid + i * 128;
    int a = idx >> 5, c4 = idx & 31;
    float4 v = *(const float4*)&emb[(size_t)fs[a] * 128 + c4 * 4];
    *(float4*)&Ls[a][c4 * 4] = v;
  }
  __syncthreads();

  {
    const int a = tid >> 1, hf = tid & 1;
    float sum = 0.f;
    #pragma unroll
    for (int j = 0; j < 16; ++j) {
      float4 lv = *(const float4*)&Ls[a][hf * 64 + j * 4];
      float4 ov = *(const float4*)&outs[hf * 64 + j * 4];
      sum += lv.x * ov.x + lv.y * ov.y + lv.z * ov.z + lv.w * ov.w;
    }
    float other = __shfl_xor(sum, 1);
    sum += other;
    if (hf == 0) hls[a] = sum + (fs[a] > 0 ? 0.0f : -1e30f);
  }
  __syncthreads();

  if (tid < 64) {
    float v = hls[tid];
    float mx = v;
    #pragma unroll
    for (int o = 32; o; o >>= 1) mx = fmaxf(mx, __shfl_xor(mx, o));
    float e = __expf(v - mx);
    float sm = e;
    #pragma unroll
    for (int o = 32; o; o >>= 1) sm += __shfl_xor(sm, o);
    wts[tid] = e / sm;
  }
  __syncthreads();

  float kv = 0.f;
  #pragma unroll 8
  for (int a2 = 0; a2 < 64; ++a2) kv += wts[a2] * Ls[a2][tid];

  S[(size_t)m * 256 + tid] = outs[tid];
  S[(size_t)m * 256 + 128 + tid] = kv;
}

// ---------------------------------------------------------------------------
extern "C" void kernel_launch(void* const* d_in, const int* in_sizes, int n_in,
                              void* d_out, int out_size, void* d_ws, size_t ws_size,
                              hipStream_t stream) {
  const float* inputs_x  = (const float*)d_in[0];
  const int*   inputs_f  = (const int*)d_in[1];
  const float* mask_seqs = (const float*)d_in[2];
  const float* dag_emb   = (const float*)d_in[3];
  const float* embed_a   = (const float*)d_in[4];
  const float* Wih0 = (const float*)d_in[5];
  const float* Whh0 = (const float*)d_in[6];
  const float* bih0 = (const float*)d_in[7];
  const float* bhh0 = (const float*)d_in[8];
  const float* Wih1 = (const float*)d_in[9];
  const float* Whh1 = (const float*)d_in[10];
  const float* bih1 = (const float*)d_in[11];
  const float* bhh1 = (const float*)d_in[12];
  const float* fc_w = (const float*)d_in[13];
  const float* fc_b = (const float*)d_in[14];
  float* out = (float*)d_out;

  float* ws = (float*)d_ws;
  float* X  = ws;             // 6400*128  =  819200
  float* xW = X  + 819200;    // 6400*384  = 2457600
  float* H1 = xW + 2457600;   // 6400*128  =  819200
  float* H2 = H1 + 819200;    // 6400*128  =  819200
  float* S  = H2 + 819200;    // 6400*256  = 1638400

  k_tanh_gemm<<<200, 256, 0, stream>>>(inputs_x, dag_emb, X);
  k_gemm_bn<128, 0><<<dim3(200, 6), 256, 0, stream>>>(X, Wih0, bih0, nullptr, xW, 384, 384);
  k_gru<<<128, 768, 0, stream>>>(xW, Whh0, bhh0, H1);
  k_gemm_bn<128, 0><<<dim3(200, 6), 256, 0, stream>>>(H1, Wih1, bih1, nullptr, xW, 384, 384);
  k_gru<<<128, 768, 0, stream>>>(xW, Whh1, bhh1, H2);
  k_attn<<<6400, 128, 0, stream>>>(H2, inputs_f, embed_a, S);
  k_gemm_bn<256, 1><<<dim3(200, 5), 256, 0, stream>>>(S, fc_w, fc_b, mask_seqs, out, 283, 283);
}

// Round 2
// 601.085 us; speedup vs baseline: 1.3998x; 1.3998x over previous
//
#include <hip/hip_runtime.h>
#include <math.h>

#define B_DIM 128
#define T_DIM 50
#define LEAF  4880
#define A_DIM 64
#define ATTN  128
#define RNN   128
#define NC    283
#define M_TOT (B_DIM*T_DIM)   // 6400
#define KSPLIT 5
#define KTILES 122            // 4880 / 40

__device__ __forceinline__ float sigmoidf_(float x) {
  return 1.0f / (1.0f + __expf(-x));
}

// ---------------------------------------------------------------------------
// K1: partial[s][6400,128] = Ax[6400, kchunk] @ Wd[kchunk, 128]
// BM=32, BN=128, BK=40 (4880 = 122*40), 256 threads, grid (200, KSPLIT)
// Split-K to fix occupancy (was 200 blocks on 256 CUs = 9.3% occupancy).
// ---------------------------------------------------------------------------
__global__ __launch_bounds__(256) void k_gemm_ksplit(
    const float* __restrict__ Ax, const float* __restrict__ Wd,
    float* __restrict__ P) {
  __shared__ __align__(16) float As[32][44];   // pad 40 -> 44
  __shared__ __align__(16) float Bs[40][128];
  const int tid = threadIdx.x;
  const int m0  = blockIdx.x * 32;
  const int s   = blockIdx.y;
  const int kt0 = (s * KTILES) / KSPLIT;
  const int kt1 = ((s + 1) * KTILES) / KSPLIT;
  const int ng  = tid & 31;   // n = ng*4
  const int mg  = tid >> 5;   // m = mg*4 + r

  // A staging indices: 320 float4 per tile, phase0: all 256, phase1: tid<64
  const int rowA0 = tid / 10, k4A0 = tid % 10;
  const int rowA1 = (tid + 256) / 10, k4A1 = (tid + 256) % 10;
  const bool ph1 = (tid + 256) < 320;
  const float* pA0 = Ax + (size_t)(m0 + rowA0) * LEAF + kt0 * 40 + k4A0 * 4;
  const float* pA1 = Ax + (size_t)(m0 + rowA1) * LEAF + kt0 * 40 + k4A1 * 4;
  // B staging indices: 1280 float4 per tile, 5 per thread
  const int brb = tid >> 5, b4 = tid & 31;
  const float* pB = Wd + (size_t)kt0 * 40 * 128 + (size_t)brb * 128 + b4 * 4;

  float4 acc[4];
  #pragma unroll
  for (int r = 0; r < 4; ++r) acc[r] = make_float4(0.f, 0.f, 0.f, 0.f);

  for (int kt = kt0; kt < kt1; ++kt) {
    // stage A tile
    {
      float4 v = *(const float4*)pA0;
      *(float4*)&As[rowA0][k4A0 * 4] = v;
      if (ph1) {
        float4 w = *(const float4*)pA1;
        *(float4*)&As[rowA1][k4A1 * 4] = w;
      }
    }
    // stage B tile
    #pragma unroll
    for (int i = 0; i < 5; ++i) {
      float4 v = *(const float4*)(pB + (size_t)i * 8 * 128);
      *(float4*)&Bs[brb + i * 8][b4 * 4] = v;
    }
    __syncthreads();

    #pragma unroll
    for (int k = 0; k < 40; k += 4) {
      float4 av[4], bv[4];
      #pragma unroll
      for (int r = 0; r < 4; ++r) av[r] = *(const float4*)&As[mg * 4 + r][k];
      #pragma unroll
      for (int kk = 0; kk < 4; ++kk) bv[kk] = *(const float4*)&Bs[k + kk][ng * 4];
      #pragma unroll
      for (int r = 0; r < 4; ++r) {
        float aa[4] = {av[r].x, av[r].y, av[r].z, av[r].w};
        #pragma unroll
        for (int kk = 0; kk < 4; ++kk) {
          acc[r].x += aa[kk] * bv[kk].x;
          acc[r].y += aa[kk] * bv[kk].y;
          acc[r].z += aa[kk] * bv[kk].z;
          acc[r].w += aa[kk] * bv[kk].w;
        }
      }
    }
    __syncthreads();
    pA0 += 40; pA1 += 40; pB += 40 * 128;
  }

  float* out = P + (size_t)s * (M_TOT * 128);
  #pragma unroll
  for (int r = 0; r < 4; ++r)
    *(float4*)&out[(size_t)(m0 + mg * 4 + r) * 128 + ng * 4] = acc[r];
}

// ---------------------------------------------------------------------------
// Reduce KSPLIT partials + tanh. X aliases P slot 0 (elementwise-safe:
// each thread reads its 5 partials, then writes its own element).
// ---------------------------------------------------------------------------
__global__ __launch_bounds__(256) void k_reduce_tanh(
    float* __restrict__ P, float* __restrict__ X) {
  const size_t i = ((size_t)blockIdx.x * 256 + threadIdx.x) * 4;
  float4 a = *(const float4*)&P[i];
  #pragma unroll
  for (int s = 1; s < KSPLIT; ++s) {
    float4 b = *(const float4*)&P[(size_t)s * (M_TOT * 128) + i];
    a.x += b.x; a.y += b.y; a.z += b.z; a.w += b.w;
  }
  a.x = tanhf(a.x); a.y = tanhf(a.y); a.z = tanhf(a.z); a.w = tanhf(a.w);
  *(float4*)&X[i] = a;
}

// ---------------------------------------------------------------------------
// Generic small GEMM: C[M,N] = A[M,K] @ Bw[N,K]^T + bias  (opt sigmoid*mask)
// BM=32, BN=64, 256 threads. A staged in LDS; B rows streamed from L2.
// ---------------------------------------------------------------------------
template<int K, int ACT>
__global__ __launch_bounds__(256) void k_gemm_bn(
    const float* __restrict__ A, const float* __restrict__ Bw,
    const float* __restrict__ bias, const float* __restrict__ maskv,
    float* __restrict__ C, int N, int ldc) {
  __shared__ __align__(16) float As[32][K + 4];
  const int tid = threadIdx.x;
  const int m0 = blockIdx.x * 32;
  const int n0 = blockIdx.y * 64;
  constexpr int K4 = K / 4;

  #pragma unroll
  for (int i = 0; i < (32 * K4) / 256; ++i) {
    int idx = tid + i * 256;
    int row = idx / K4, k4 = idx % K4;
    float4 v = *(const float4*)&A[(size_t)(m0 + row) * K + k4 * 4];
    *(float4*)&As[row][k4 * 4] = v;
  }
  __syncthreads();

  const int n2 = tid & 31, mg = tid >> 5;
  const int n = n0 + n2 * 2;
  const int ns0 = min(n, N - 1), ns1 = min(n + 1, N - 1);
  const float* Bp0 = Bw + (size_t)ns0 * K;
  const float* Bp1 = Bw + (size_t)ns1 * K;

  float acc[4][2] = {};
  #pragma unroll 4
  for (int k = 0; k < K; k += 4) {
    float4 b0 = *(const float4*)&Bp0[k];
    float4 b1 = *(const float4*)&Bp1[k];
    #pragma unroll
    for (int r = 0; r < 4; ++r) {
      float4 a = *(const float4*)&As[mg * 4 + r][k];
      acc[r][0] += a.x * b0.x + a.y * b0.y + a.z * b0.z + a.w * b0.w;
      acc[r][1] += a.x * b1.x + a.y * b1.y + a.z * b1.z + a.w * b1.w;
    }
  }

  #pragma unroll
  for (int r = 0; r < 4; ++r) {
    int m = m0 + mg * 4 + r;
    #pragma unroll
    for (int c = 0; c < 2; ++c) {
      int nn = n + c;
      if (nn < N) {
        float v = acc[r][c] + bias[nn];
        if (ACT) v = sigmoidf_(v) * maskv[m];
        C[(size_t)m * ldc + nn] = v;
      }
    }
  }
}

// ---------------------------------------------------------------------------
// GRU scan, one layer. One block per batch row; 768 threads.
// Thread pair (g = tid>>1) owns Whh row g; half hf = tid&1 does 64 of the 128 MACs.
// xW = precomputed x@Wih^T + bih, layout [(b*50+t)*384 + g].
// ---------------------------------------------------------------------------
__global__ __launch_bounds__(768) void k_gru(
    const float* __restrict__ xW, const float* __restrict__ Whh,
    const float* __restrict__ bhh, float* __restrict__ Hout) {
  const int b = blockIdx.x;
  const int tid = threadIdx.x;
  const int g = tid >> 1;
  const int hf = tid & 1;
  __shared__ __align__(16) float hs[128];
  __shared__ float ghs[384];

  float4 w4[16];
  #pragma unroll
  for (int k = 0; k < 16; ++k)
    w4[k] = *(const float4*)&Whh[(size_t)g * 128 + hf * 64 + k * 4];
  const float bh = bhh[g];

  if (tid < 128) hs[tid] = 0.0f;
  __syncthreads();

  for (int t = 0; t < 50; ++t) {
    float acc = 0.f;
    #pragma unroll
    for (int k = 0; k < 16; ++k) {
      float4 hv = *(const float4*)&hs[hf * 64 + k * 4];
      acc += w4[k].x * hv.x + w4[k].y * hv.y + w4[k].z * hv.z + w4[k].w * hv.w;
    }
    float other = __shfl_xor(acc, 1);
    acc += other;
    if (hf == 0) ghs[g] = acc + bh;
    __syncthreads();
    if (tid < 128) {
      const int j = tid;
      const float* xw = &xW[(size_t)(b * 50 + t) * 384];
      float r = sigmoidf_(xw[j] + ghs[j]);
      float z = sigmoidf_(xw[128 + j] + ghs[128 + j]);
      float nn = tanhf(xw[256 + j] + r * ghs[256 + j]);
      float h = (1.f - z) * nn + z * hs[j];
      hs[j] = h;
      Hout[(size_t)(b * 50 + t) * 128 + j] = h;
    }
    __syncthreads();
  }
}

// ---------------------------------------------------------------------------
// Attention: per (b,t) block (6400 blocks, 128 threads).
// ---------------------------------------------------------------------------
__global__ __launch_bounds__(128) void k_attn(
    const float* __restrict__ H2, const int* __restrict__ F,
    const float* __restrict__ emb, float* __restrict__ S) {
  const int m = blockIdx.x;
  const int tid = threadIdx.x;
  __shared__ __align__(16) float outs[128];
  __shared__ __align__(16) float Ls[64][132];
  __shared__ float hls[64];
  __shared__ float wts[64];
  __shared__ int fs[64];

  outs[tid] = H2[(size_t)m * 128 + tid];
  if (tid < 64) fs[tid] = F[(size_t)m * 64 + tid];
  __syncthreads();

  #pragma unroll
  for (int i = 0; i < 16; ++i) {
    int idx = tid + i * 128;
    int a = idx >> 5, c4 = idx & 31;
    float4 v = *(const float4*)&emb[(size_t)fs[a] * 128 + c4 * 4];
    *(float4*)&Ls[a][c4 * 4] = v;
  }
  __syncthreads();

  {
    const int a = tid >> 1, hf = tid & 1;
    float sum = 0.f;
    #pragma unroll
    for (int j = 0; j < 16; ++j) {
      float4 lv = *(const float4*)&Ls[a][hf * 64 + j * 4];
      float4 ov = *(const float4*)&outs[hf * 64 + j * 4];
      sum += lv.x * ov.x + lv.y * ov.y + lv.z * ov.z + lv.w * ov.w;
    }
    float other = __shfl_xor(sum, 1);
    sum += other;
    if (hf == 0) hls[a] = sum + (fs[a] > 0 ? 0.0f : -1e30f);
  }
  __syncthreads();

  if (tid < 64) {
    float v = hls[tid];
    float mx = v;
    #pragma unroll
    for (int o = 32; o; o >>= 1) mx = fmaxf(mx, __shfl_xor(mx, o));
    float e = __expf(v - mx);
    float sm = e;
    #pragma unroll
    for (int o = 32; o; o >>= 1) sm += __shfl_xor(sm, o);
    wts[tid] = e / sm;
  }
  __syncthreads();

  float kv = 0.f;
  #pragma unroll 8
  for (int a2 = 0; a2 < 64; ++a2) kv += wts[a2] * Ls[a2][tid];

  S[(size_t)m * 256 + tid] = outs[tid];
  S[(size_t)m * 256 + 128 + tid] = kv;
}

// ---------------------------------------------------------------------------
extern "C" void kernel_launch(void* const* d_in, const int* in_sizes, int n_in,
                              void* d_out, int out_size, void* d_ws, size_t ws_size,
                              hipStream_t stream) {
  const float* inputs_x  = (const float*)d_in[0];
  const int*   inputs_f  = (const int*)d_in[1];
  const float* mask_seqs = (const float*)d_in[2];
  const float* dag_emb   = (const float*)d_in[3];
  const float* embed_a   = (const float*)d_in[4];
  const float* Wih0 = (const float*)d_in[5];
  const float* Whh0 = (const float*)d_in[6];
  const float* bih0 = (const float*)d_in[7];
  const float* bhh0 = (const float*)d_in[8];
  const float* Wih1 = (const float*)d_in[9];
  const float* Whh1 = (const float*)d_in[10];
  const float* bih1 = (const float*)d_in[11];
  const float* bhh1 = (const float*)d_in[12];
  const float* fc_w = (const float*)d_in[13];
  const float* fc_b = (const float*)d_in[14];
  float* out = (float*)d_out;

  float* ws = (float*)d_ws;
  // Layout (floats), with aliasing:
  //   P  = ws .. +5*819200 (4,096,000)  split-K partials
  //   X  aliases P slot 0 (reduce is elementwise in-place safe)
  //   S  aliases P slots 1-2 (P dead after reduce; X alive until xW0 done)
  float* P  = ws;
  float* X  = P;                       // 819200
  float* S  = P + 819200;              // 1638400 (into P slots 1-2)
  float* xW = ws + KSPLIT * 819200;    // 2457600
  float* H1 = xW + 2457600;            // 819200
  float* H2 = H1 + 819200;             // 819200

  k_gemm_ksplit<<<dim3(200, KSPLIT), 256, 0, stream>>>(inputs_x, dag_emb, P);
  k_reduce_tanh<<<800, 256, 0, stream>>>(P, X);
  k_gemm_bn<128, 0><<<dim3(200, 6), 256, 0, stream>>>(X, Wih0, bih0, nullptr, xW, 384, 384);
  k_gru<<<128, 768, 0, stream>>>(xW, Whh0, bhh0, H1);
  k_gemm_bn<128, 0><<<dim3(200, 6), 256, 0, stream>>>(H1, Wih1, bih1, nullptr, xW, 384, 384);
  k_gru<<<128, 768, 0, stream>>>(xW, Whh1, bhh1, H2);
  k_attn<<<6400, 128, 0, stream>>>(H2, inputs_f, embed_a, S);
  k_gemm_bn<256, 1><<<dim3(200, 5), 256, 0, stream>>>(S, fc_w, fc_b, mask_seqs, out, 283, 283);
}